// Round 17
// baseline (2588.290 us; speedup 1.0000x reference)
//
#include <hip/hip_runtime.h>
#include <hip/hip_bf16.h>

#define NN 50000
#define NROWS (NN + 1)           // +1 sentinel zero row
#define NE 1600000
#define NEPAD 1951024            // >= NE + 7*NN = 1,950,000; multiple of 4
#define DIM 128
#define NG 64
#define EPSV 1e-5f
#define NCHUNK 49                // ceil(50000/1024)
#define UNROLL 8                 // table rows in flight per wave
#define RUN 4                    // nodes per wave in pool kernel
#define NXCD 8
#define SHARD_COLS (NN / NXCD)   // 6250
#define SHARD_CAP 220000         // max edges/shard (NE/8=200000 + slack)
#define STG_BLOCKS 2048
#define FILL2_CHUNKS 128         // fill2 grid = 8 * FILL2_CHUNKS

typedef __attribute__((ext_vector_type(8))) __bf16 bf16x8;
typedef __attribute__((ext_vector_type(2))) __bf16 bf16x2;
typedef __attribute__((ext_vector_type(16))) float f32x16;

// ---------------- CSR build ----------------

// pre-fill padded esrc with sentinel NN (points at the zero row)
__global__ void sentinel_kernel(int4* __restrict__ esrc4) {
    const int4 v = {NN, NN, NN, NN};
    for (int i = blockIdx.x * 256 + threadIdx.x; i < NEPAD / 4; i += gridDim.x * 256)
        esrc4[i] = v;
}

// One pass over edges: degree count + compact (col,row) pairs into 8
// per-shard staging lists. WAVE-level aggregation (ballot/popc/shfl):
// one shard_tail atomic per (wave, shard) -- no LDS, no barriers.
__global__ void __launch_bounds__(256) stage_kernel(
    const int* __restrict__ erow, const int* __restrict__ ecol,
    int* __restrict__ cnt, int* __restrict__ shard_tail,
    int2* __restrict__ staging) {
    const int lane = threadIdx.x & 63;
    const unsigned long long lt = (lane == 63) ? 0x7fffffffffffffffull
                                               : ((1ull << lane) - 1);
    for (int e = blockIdx.x * 256 + threadIdx.x; e < NE; e += STG_BLOCKS * 256) {
        const int c = ecol[e];
        const int r = erow[e];
        atomicAdd(&cnt[c], 1);               // degree count (fused)
        const int sh = c / SHARD_COLS;
#pragma unroll
        for (int s = 0; s < NXCD; s++) {
            const unsigned long long m = __ballot(sh == s);
            if (m == 0) continue;            // wave-uniform
            const int leader = __ffsll((long long)m) - 1;
            int base = 0;
            if (lane == leader) base = atomicAdd(&shard_tail[s], __popcll(m));
            base = __shfl(base, leader);
            if (sh == s) {
                const int p = base + (int)__popcll(m & lt);
                int2 pr; pr.x = c; pr.y = r;
                staging[(size_t)s * SHARD_CAP + p] = pr;
            }
        }
    }
}

// scan PADDED degrees: pdeg = ceil(cnt/8)*8 (self-loop handled separately)
__global__ void scan_chunk(const int* __restrict__ cnt, int* __restrict__ excl,
                           int* __restrict__ csum) {
    __shared__ int lds[256];
    int t = threadIdx.x;
    int base = blockIdx.x * 1024 + t * 4;
    int v0 = (base + 0 < NN) ? ((cnt[base + 0] + 7) & ~7) : 0;
    int v1 = (base + 1 < NN) ? ((cnt[base + 1] + 7) & ~7) : 0;
    int v2 = (base + 2 < NN) ? ((cnt[base + 2] + 7) & ~7) : 0;
    int v3 = (base + 3 < NN) ? ((cnt[base + 3] + 7) & ~7) : 0;
    int s = v0 + v1 + v2 + v3;
    lds[t] = s;
    __syncthreads();
    for (int off = 1; off < 256; off <<= 1) {
        int x = (t >= off) ? lds[t - off] : 0;
        __syncthreads();
        lds[t] += x;
        __syncthreads();
    }
    int run = lds[t] - s;           // exclusive prefix within chunk
    if (t == 255) csum[blockIdx.x] = lds[t];
    if (base + 0 < NN) excl[base + 0] = run; run += v0;
    if (base + 1 < NN) excl[base + 1] = run; run += v1;
    if (base + 2 < NN) excl[base + 2] = run; run += v2;
    if (base + 3 < NN) excl[base + 3] = run;
}

__global__ void scan_tail(const int* __restrict__ csum, int* __restrict__ coff,
                          int* __restrict__ row_ptr, int nch) {
    int l = threadIdx.x;
    int v = (l < nch) ? csum[l] : 0;
    int s = v;
    for (int o = 1; o < 64; o <<= 1) {
        int x = __shfl_up(s, o);
        if (l >= o) s += x;
    }
    if (l < nch) coff[l] = s - v;   // exclusive chunk offsets
    if (l == nch - 1) row_ptr[NN] = s;   // total padded edges
}

__global__ void fixup_kernel(int* __restrict__ row_ptr, const int* __restrict__ coff,
                             const int* __restrict__ cnt, float* __restrict__ dinv,
                             int* __restrict__ cursor) {
    int n = blockIdx.x * 256 + threadIdx.x;
    if (n < NN) {
        int rp = row_ptr[n] + coff[n >> 10];
        row_ptr[n] = rp;
        cursor[n] = rp;
        dinv[n] = rsqrtf((float)(cnt[n] + 1));   // +1 for self-loop
    }
}

// Scatter from per-shard compact lists. Block b handles shard (b&7): its
// staging list, cursor slice and esrc slice all fit that XCD's L2, so esrc
// lines fill completely before writeback (no streaming pollution). r16
// validated this at ~24us.
__global__ void __launch_bounds__(256) fill2_kernel(
    const int2* __restrict__ staging, const int* __restrict__ shard_tail,
    int* __restrict__ cursor, int* __restrict__ esrc) {
    const int sh = blockIdx.x & (NXCD - 1);
    const int chunk = blockIdx.x >> 3;
    const int m = shard_tail[sh];
    const int2* __restrict__ sp = staging + (size_t)sh * SHARD_CAP;
    for (int i = chunk * 256 + threadIdx.x; i < m; i += FILL2_CHUNKS * 256) {
        const int2 pr = sp[i];
        const int pos = atomicAdd(&cursor[pr.x], 1);
        esrc[pos] = pr.y;
    }
}

// fold bias+BN into per-col scale/shift; zero the sentinel row of tbuf.
__global__ void bn_prep_kernel(const float* __restrict__ b1, const float* __restrict__ g1,
                               const float* __restrict__ be1, const float* __restrict__ rm1,
                               const float* __restrict__ rv1,
                               const float* __restrict__ b2, const float* __restrict__ g2,
                               const float* __restrict__ be2, const float* __restrict__ rm2,
                               const float* __restrict__ rv2,
                               float* __restrict__ sc1, float* __restrict__ sh1,
                               float* __restrict__ sc2, float* __restrict__ sh2,
                               __bf16* __restrict__ tbuf) {
    int c = threadIdx.x;
    if (c < DIM) {
        float s1 = g1[c] * rsqrtf(rv1[c] + EPSV);
        sc1[c] = s1;
        sh1[c] = (b1[c] - rm1[c]) * s1 + be1[c];
        float s2 = g2[c] * rsqrtf(rv2[c] + EPSV);
        sc2[c] = s2;
        sh2[c] = (b2[c] - rm2[c]) * s2 + be2[c];
        tbuf[(size_t)NN * DIM + c] = (__bf16)0.f;   // sentinel row, persists all layers
    }
}

// ---------------- dense: (h @ W) * dinv[row] -> bf16 table ----------------

__device__ __forceinline__ bf16x8 load8(const float* p) {
    float4 lo = ((const float4*)p)[0], hi = ((const float4*)p)[1];
    bf16x8 a;
    a[0] = (__bf16)lo.x; a[1] = (__bf16)lo.y; a[2] = (__bf16)lo.z; a[3] = (__bf16)lo.w;
    a[4] = (__bf16)hi.x; a[5] = (__bf16)hi.y; a[6] = (__bf16)hi.z; a[7] = (__bf16)hi.w;
    return a;
}
__device__ __forceinline__ bf16x8 load8(const __bf16* p) {
    return *(const bf16x8*)p;
}

template <typename T>
__global__ void __launch_bounds__(256) matmul_kernel(const T* __restrict__ h,
                                                     const float* __restrict__ W,
                                                     const float* __restrict__ dinv,
                                                     __bf16* __restrict__ t) {
    const int wave = threadIdx.x >> 6;
    const int lane = threadIdx.x & 63;
    const int col = wave * 32 + (lane & 31);
    const int khalf = (lane >> 5) * 8;   // 0 or 8

    bf16x8 b[8];
#pragma unroll
    for (int kc = 0; kc < 8; kc++) {
#pragma unroll
        for (int j = 0; j < 8; j++) {
            b[kc][j] = (__bf16)W[(kc * 16 + khalf + j) * DIM + col];
        }
    }

    const int ntiles = (NN + 31) / 32;
    for (int tile = blockIdx.x; tile < ntiles; tile += gridDim.x) {
        const int arow = tile * 32 + (lane & 31);
        const int arow_c = (arow < NN) ? arow : (NN - 1);  // clamped load; bad rows not stored
        f32x16 acc = {};
#pragma unroll
        for (int kc = 0; kc < 8; kc++) {
            bf16x8 a = load8(h + (size_t)arow_c * DIM + kc * 16 + khalf);
            acc = __builtin_amdgcn_mfma_f32_32x32x16_bf16(a, b[kc], acc, 0, 0, 0);
        }
#pragma unroll
        for (int r = 0; r < 16; r++) {
            int orow = tile * 32 + (r & 3) + 8 * (r >> 2) + 4 * (lane >> 5);
            if (orow < NN) t[(size_t)orow * DIM + col] = (__bf16)(acc[r] * dinv[orow]);
        }
    }
}

// ---------------- sparse: pull-gather, full-row, sentinel-padded ----------
// One wave per node; lane handles cols {2*lane, 2*lane+1}; one instruction
// reads one full 256B table row (1 contiguous segment -- the proven optimal
// shape, r10/r14/r15 A/B). Edge lists padded to x8 with sentinel row NN
// (zeros): wave-uniform bounds, zero predication. UNROLL=8 rows in flight.

__device__ __forceinline__ float lo16(unsigned u) { return __uint_as_float(u << 16); }
__device__ __forceinline__ float hi16(unsigned u) { return __uint_as_float(u & 0xffff0000u); }

__device__ __forceinline__ void gather_core(
    const unsigned* __restrict__ t32, const int* __restrict__ esrc,
    int beg, int end, int lane, float& ax, float& ay) {
    for (int e = beg; e < end; e += UNROLL) {    // end-beg is a multiple of 8
        int s[UNROLL];
        unsigned u[UNROLL];
#pragma unroll
        for (int i = 0; i < UNROLL; i++) s[i] = esrc[e + i];   // wave-uniform -> s_load
#pragma unroll
        for (int i = 0; i < UNROLL; i++) {
            const unsigned idx = ((unsigned)s[i] << 6) + lane;
            u[i] = t32[idx];
        }
#pragma unroll
        for (int i = 0; i < UNROLL; i++) {
            ax += lo16(u[i]);
            ay += hi16(u[i]);
        }
    }
}

__global__ void __launch_bounds__(256) gather_bn_kernel(
    const unsigned* __restrict__ t32, const int* __restrict__ row_ptr,
    const int* __restrict__ esrc, const float* __restrict__ dinv,
    const float* __restrict__ scale, const float* __restrict__ shift,
    __bf16* __restrict__ out) {
    const int lane = threadIdx.x & 63;
    const int n = __builtin_amdgcn_readfirstlane(blockIdx.x * 4 + (threadIdx.x >> 6));
    if (n >= NN) return;
    float ax = 0.f, ay = 0.f;
    const int beg = row_ptr[n], end = row_ptr[n + 1];
    gather_core(t32, esrc, beg, end, lane, ax, ay);
    {   // self loop (weight 1; dinv[n] applied below)
        const unsigned u = t32[((unsigned)n << 6) + lane];
        ax += lo16(u); ay += hi16(u);
    }
    const float dv = dinv[n];
    const int c0 = lane * 2, c1 = c0 + 1;
    const float vx = fmaxf(fmaf(ax, dv * scale[c0], shift[c0]), 0.f);
    const float vy = fmaxf(fmaf(ay, dv * scale[c1], shift[c1]), 0.f);
    bf16x2 o; o[0] = (__bf16)vx; o[1] = (__bf16)vy;
    *(bf16x2*)(out + (size_t)n * DIM + c0) = o;
}

// Pool: batch is SORTED -> segment reduction over RUN nodes per wave; flush
// atomics only at graph boundary / run end.

__global__ void __launch_bounds__(256) gather_pool_kernel(
    const unsigned* __restrict__ t32, const int* __restrict__ row_ptr,
    const int* __restrict__ esrc, const float* __restrict__ dinv,
    const float* __restrict__ bias, const int* __restrict__ batch,
    float* __restrict__ out) {
    const int lane = threadIdx.x & 63;
    const int wid = __builtin_amdgcn_readfirstlane(blockIdx.x * 4 + (threadIdx.x >> 6));
    const int n0 = wid * RUN;            // NN % RUN == 0
    if (n0 >= NN) return;
    const int c0 = lane * 2, c1 = c0 + 1;
    const float bx = bias[c0], by = bias[c1];
    float rx = 0.f, ry = 0.f;
    int g = batch[n0];
    for (int j = 0; j < RUN; j++) {
        const int n = n0 + j;
        float ax = 0.f, ay = 0.f;
        const int beg = row_ptr[n], end = row_ptr[n + 1];
        gather_core(t32, esrc, beg, end, lane, ax, ay);
        {
            const unsigned u = t32[((unsigned)n << 6) + lane];
            ax += lo16(u); ay += hi16(u);
        }
        const float dv = dinv[n];
        const int gn = batch[n];
        if (gn != g) {   // graph boundary: flush previous segment (uniform branch)
            atomicAdd(out + (size_t)g * DIM + c0, rx);
            atomicAdd(out + (size_t)g * DIM + c1, ry);
            rx = 0.f; ry = 0.f; g = gn;
        }
        rx += fmaf(ax, dv, bx);
        ry += fmaf(ay, dv, by);
    }
    atomicAdd(out + (size_t)g * DIM + c0, rx);
    atomicAdd(out + (size_t)g * DIM + c1, ry);
}

// ---------------- launch ----------------

extern "C" void kernel_launch(void* const* d_in, const int* in_sizes, int n_in,
                              void* d_out, int out_size, void* d_ws, size_t ws_size,
                              hipStream_t stream) {
    const float* x    = (const float*)d_in[0];
    const int*   ei   = (const int*)d_in[1];
    const int*   batch= (const int*)d_in[2];
    const float* W1 = (const float*)d_in[3];
    const float* b1 = (const float*)d_in[4];
    const float* W2 = (const float*)d_in[5];
    const float* b2 = (const float*)d_in[6];
    const float* W3 = (const float*)d_in[7];
    const float* b3 = (const float*)d_in[8];
    const float* g1 = (const float*)d_in[9];
    const float* be1= (const float*)d_in[10];
    const float* rm1= (const float*)d_in[11];
    const float* rv1= (const float*)d_in[12];
    const float* g2 = (const float*)d_in[13];
    const float* be2= (const float*)d_in[14];
    const float* rm2= (const float*)d_in[15];
    const float* rv2= (const float*)d_in[16];
    const int* erow = ei;
    const int* ecol = ei + NE;

    char* ws = (char*)d_ws;
    size_t off = 0;
    auto alloc = [&](size_t bytes) -> void* {
        void* p = ws + off;
        off = (off + bytes + 255) & ~(size_t)255;
        return p;
    };
    int*    cnt     = (int*)alloc(NN * sizeof(int));
    int*    row_ptr = (int*)alloc((NN + 1) * sizeof(int));
    int*    cursor  = (int*)alloc(NN * sizeof(int));
    int*    csum    = (int*)alloc(64 * sizeof(int));
    int*    coff    = (int*)alloc(64 * sizeof(int));
    float*  dinv    = (float*)alloc(NN * sizeof(float));
    int*    stail   = (int*)alloc(NXCD * sizeof(int));
    int*    esrc    = (int*)alloc(NEPAD * sizeof(int));
    int2*   staging = (int2*)alloc((size_t)NXCD * SHARD_CAP * sizeof(int2));
    __bf16* tbuf    = (__bf16*)alloc((size_t)NROWS * DIM * sizeof(__bf16));
    __bf16* hbuf    = (__bf16*)alloc((size_t)NN * DIM * sizeof(__bf16));
    float*  sc1     = (float*)alloc(DIM * sizeof(float));
    float*  sh1     = (float*)alloc(DIM * sizeof(float));
    float*  sc2     = (float*)alloc(DIM * sizeof(float));
    float*  sh2     = (float*)alloc(DIM * sizeof(float));

    hipMemsetAsync(cnt, 0, NN * sizeof(int), stream);
    hipMemsetAsync(stail, 0, NXCD * sizeof(int), stream);
    hipMemsetAsync(d_out, 0, NG * DIM * sizeof(float), stream);

    bn_prep_kernel<<<1, 128, 0, stream>>>(b1, g1, be1, rm1, rv1,
                                          b2, g2, be2, rm2, rv2,
                                          sc1, sh1, sc2, sh2, tbuf);
    sentinel_kernel<<<512, 256, 0, stream>>>((int4*)esrc);
    stage_kernel<<<STG_BLOCKS, 256, 0, stream>>>(erow, ecol, cnt, stail, staging);
    scan_chunk<<<NCHUNK, 256, 0, stream>>>(cnt, row_ptr, csum);
    scan_tail<<<1, 64, 0, stream>>>(csum, coff, row_ptr, NCHUNK);
    fixup_kernel<<<(NN + 255) / 256, 256, 0, stream>>>(row_ptr, coff, cnt, dinv, cursor);
    fill2_kernel<<<NXCD * FILL2_CHUNKS, 256, 0, stream>>>(staging, stail, cursor, esrc);

    const unsigned* t32 = (const unsigned*)tbuf;
    const int nblk = (NN + 3) / 4;
    const int nblk_pool = (NN / RUN + 3) / 4;

    matmul_kernel<float><<<512, 256, 0, stream>>>(x, W1, dinv, tbuf);
    gather_bn_kernel<<<nblk, 256, 0, stream>>>(t32, row_ptr, esrc, dinv,
                                               sc1, sh1, hbuf);
    matmul_kernel<__bf16><<<512, 256, 0, stream>>>(hbuf, W2, dinv, tbuf);
    gather_bn_kernel<<<nblk, 256, 0, stream>>>(t32, row_ptr, esrc, dinv,
                                               sc2, sh2, hbuf);
    matmul_kernel<__bf16><<<512, 256, 0, stream>>>(hbuf, W3, dinv, tbuf);
    gather_pool_kernel<<<nblk_pool, 256, 0, stream>>>(t32, row_ptr, esrc, dinv,
                                                      b3, batch, (float*)d_out);
}

// Round 18
// 607.665 us; speedup vs baseline: 4.2594x; 4.2594x over previous
//
#include <hip/hip_runtime.h>
#include <hip/hip_bf16.h>

#define NN 50000
#define NROWS (NN + 1)           // +1 sentinel zero row
#define NE 1600000
#define NEPAD 1951024            // >= NE + 7*NN = 1,950,000; multiple of 4
#define DIM 128
#define NG 64
#define EPSV 1e-5f
#define NCHUNK 49                // ceil(50000/1024)
#define UNROLL 8                 // table rows in flight per wave
#define RUN 4                    // nodes per wave in pool kernel
#define NXCD 8
#define SHARD_COLS (NN / NXCD)   // 6250
#define SHARD_CAP 220000         // max edges/shard (NE/8=200000 + slack)
#define NBATCH (NE / 64)         // 25000 64-edge batches
#define PASS_BLOCKS 2048
#define NWAVES (PASS_BLOCKS * 4)
#define FILL2_CHUNKS 128         // fill2 grid = 8 * FILL2_CHUNKS

typedef __attribute__((ext_vector_type(8))) __bf16 bf16x8;
typedef __attribute__((ext_vector_type(2))) __bf16 bf16x2;
typedef __attribute__((ext_vector_type(16))) float f32x16;

// ---------------- CSR build ----------------

// pre-fill padded esrc with sentinel NN (points at the zero row)
__global__ void sentinel_kernel(int4* __restrict__ esrc4) {
    const int4 v = {NN, NN, NN, NN};
    for (int i = blockIdx.x * 256 + threadIdx.x; i < NEPAD / 4; i += gridDim.x * 256)
        esrc4[i] = v;
}

// Pass A: fused degree count + per-(batch,shard) ballot counts.
// No contended atomics (cnt has 50K addresses), no barriers.
__global__ void __launch_bounds__(256) passA_kernel(
    const int* __restrict__ ecol, int* __restrict__ cnt, int* __restrict__ wcnt) {
    const int lane = threadIdx.x & 63;
    const int gw = (blockIdx.x * 256 + threadIdx.x) >> 6;
    for (int bi = gw; bi < NBATCH; bi += NWAVES) {
        const int c = ecol[bi * 64 + lane];
        atomicAdd(&cnt[c], 1);
        const int sh = c / SHARD_COLS;
        int myc = 0;
#pragma unroll
        for (int s = 0; s < NXCD; s++) {
            const unsigned long long m = __ballot(sh == s);
            if (lane == s) myc = (int)__popcll(m);
        }
        if (lane < NXCD) wcnt[bi * NXCD + lane] = myc;
    }
}

// Exclusive-scan wcnt per shard (8 waves, shfl-based; no barriers, no atomics).
__global__ void sscan_kernel(int* __restrict__ wcnt, int* __restrict__ stail) {
    const int w = threadIdx.x >> 6;      // shard 0..7
    const int lane = threadIdx.x & 63;
    int carry = 0;
    for (int base = 0; base < NBATCH; base += 64) {
        const int bi = base + lane;
        const int v = (bi < NBATCH) ? wcnt[bi * NXCD + w] : 0;
        int inc = v;
#pragma unroll
        for (int o = 1; o < 64; o <<= 1) {
            const int x = __shfl_up(inc, o);
            if (lane >= o) inc += x;
        }
        if (bi < NBATCH) wcnt[bi * NXCD + w] = carry + inc - v;   // exclusive base
        carry += __shfl(inc, 63);
    }
    if (lane == 0) stail[w] = carry;
}

// Pass B: recompute the identical ballots; deterministic placement at
// base + popc(mask & below). Zero atomics, zero barriers; writes are
// contiguous runs per (wave, shard).
__global__ void __launch_bounds__(256) passB_kernel(
    const int* __restrict__ erow, const int* __restrict__ ecol,
    const int* __restrict__ wcnt, int2* __restrict__ staging) {
    const int lane = threadIdx.x & 63;
    const unsigned long long lt = (1ull << lane) - 1;   // lanes strictly below
    const int gw = (blockIdx.x * 256 + threadIdx.x) >> 6;
    for (int bi = gw; bi < NBATCH; bi += NWAVES) {
        const int e = bi * 64 + lane;
        const int c = ecol[e];
        const int r = erow[e];
        const int sh = c / SHARD_COLS;
#pragma unroll
        for (int s = 0; s < NXCD; s++) {
            const unsigned long long m = __ballot(sh == s);
            if (sh == s) {
                const int off = (int)__popcll(m & lt);
                const int base = wcnt[bi * NXCD + s];
                int2 pr; pr.x = c; pr.y = r;
                staging[(size_t)s * SHARD_CAP + base + off] = pr;
            }
        }
    }
}

// scan PADDED degrees: pdeg = ceil(cnt/8)*8 (self-loop handled separately)
__global__ void scan_chunk(const int* __restrict__ cnt, int* __restrict__ excl,
                           int* __restrict__ csum) {
    __shared__ int lds[256];
    int t = threadIdx.x;
    int base = blockIdx.x * 1024 + t * 4;
    int v0 = (base + 0 < NN) ? ((cnt[base + 0] + 7) & ~7) : 0;
    int v1 = (base + 1 < NN) ? ((cnt[base + 1] + 7) & ~7) : 0;
    int v2 = (base + 2 < NN) ? ((cnt[base + 2] + 7) & ~7) : 0;
    int v3 = (base + 3 < NN) ? ((cnt[base + 3] + 7) & ~7) : 0;
    int s = v0 + v1 + v2 + v3;
    lds[t] = s;
    __syncthreads();
    for (int off = 1; off < 256; off <<= 1) {
        int x = (t >= off) ? lds[t - off] : 0;
        __syncthreads();
        lds[t] += x;
        __syncthreads();
    }
    int run = lds[t] - s;           // exclusive prefix within chunk
    if (t == 255) csum[blockIdx.x] = lds[t];
    if (base + 0 < NN) excl[base + 0] = run; run += v0;
    if (base + 1 < NN) excl[base + 1] = run; run += v1;
    if (base + 2 < NN) excl[base + 2] = run; run += v2;
    if (base + 3 < NN) excl[base + 3] = run;
}

__global__ void scan_tail(const int* __restrict__ csum, int* __restrict__ coff,
                          int* __restrict__ row_ptr, int nch) {
    int l = threadIdx.x;
    int v = (l < nch) ? csum[l] : 0;
    int s = v;
    for (int o = 1; o < 64; o <<= 1) {
        int x = __shfl_up(s, o);
        if (l >= o) s += x;
    }
    if (l < nch) coff[l] = s - v;   // exclusive chunk offsets
    if (l == nch - 1) row_ptr[NN] = s;   // total padded edges
}

__global__ void fixup_kernel(int* __restrict__ row_ptr, const int* __restrict__ coff,
                             const int* __restrict__ cnt, float* __restrict__ dinv,
                             int* __restrict__ cursor) {
    int n = blockIdx.x * 256 + threadIdx.x;
    if (n < NN) {
        int rp = row_ptr[n] + coff[n >> 10];
        row_ptr[n] = rp;
        cursor[n] = rp;
        dinv[n] = rsqrtf((float)(cnt[n] + 1));   // +1 for self-loop
    }
}

// Scatter from per-shard compact lists. Block b handles shard (b&7): its
// staging list, cursor slice and esrc slice all fit that XCD's L2, so esrc
// lines fill completely before writeback. r16-validated at ~23us.
__global__ void __launch_bounds__(256) fill2_kernel(
    const int2* __restrict__ staging, const int* __restrict__ shard_tail,
    int* __restrict__ cursor, int* __restrict__ esrc) {
    const int sh = blockIdx.x & (NXCD - 1);
    const int chunk = blockIdx.x >> 3;
    const int m = shard_tail[sh];
    const int2* __restrict__ sp = staging + (size_t)sh * SHARD_CAP;
    for (int i = chunk * 256 + threadIdx.x; i < m; i += FILL2_CHUNKS * 256) {
        const int2 pr = sp[i];
        const int pos = atomicAdd(&cursor[pr.x], 1);
        esrc[pos] = pr.y;
    }
}

// fold bias+BN into per-col scale/shift; zero the sentinel row of tbuf.
__global__ void bn_prep_kernel(const float* __restrict__ b1, const float* __restrict__ g1,
                               const float* __restrict__ be1, const float* __restrict__ rm1,
                               const float* __restrict__ rv1,
                               const float* __restrict__ b2, const float* __restrict__ g2,
                               const float* __restrict__ be2, const float* __restrict__ rm2,
                               const float* __restrict__ rv2,
                               float* __restrict__ sc1, float* __restrict__ sh1,
                               float* __restrict__ sc2, float* __restrict__ sh2,
                               __bf16* __restrict__ tbuf) {
    int c = threadIdx.x;
    if (c < DIM) {
        float s1 = g1[c] * rsqrtf(rv1[c] + EPSV);
        sc1[c] = s1;
        sh1[c] = (b1[c] - rm1[c]) * s1 + be1[c];
        float s2 = g2[c] * rsqrtf(rv2[c] + EPSV);
        sc2[c] = s2;
        sh2[c] = (b2[c] - rm2[c]) * s2 + be2[c];
        tbuf[(size_t)NN * DIM + c] = (__bf16)0.f;   // sentinel row, persists all layers
    }
}

// ---------------- dense: (h @ W) * dinv[row] -> bf16 table ----------------

__device__ __forceinline__ bf16x8 load8(const float* p) {
    float4 lo = ((const float4*)p)[0], hi = ((const float4*)p)[1];
    bf16x8 a;
    a[0] = (__bf16)lo.x; a[1] = (__bf16)lo.y; a[2] = (__bf16)lo.z; a[3] = (__bf16)lo.w;
    a[4] = (__bf16)hi.x; a[5] = (__bf16)hi.y; a[6] = (__bf16)hi.z; a[7] = (__bf16)hi.w;
    return a;
}
__device__ __forceinline__ bf16x8 load8(const __bf16* p) {
    return *(const bf16x8*)p;
}

template <typename T>
__global__ void __launch_bounds__(256) matmul_kernel(const T* __restrict__ h,
                                                     const float* __restrict__ W,
                                                     const float* __restrict__ dinv,
                                                     __bf16* __restrict__ t) {
    const int wave = threadIdx.x >> 6;
    const int lane = threadIdx.x & 63;
    const int col = wave * 32 + (lane & 31);
    const int khalf = (lane >> 5) * 8;   // 0 or 8

    bf16x8 b[8];
#pragma unroll
    for (int kc = 0; kc < 8; kc++) {
#pragma unroll
        for (int j = 0; j < 8; j++) {
            b[kc][j] = (__bf16)W[(kc * 16 + khalf + j) * DIM + col];
        }
    }

    const int ntiles = (NN + 31) / 32;
    for (int tile = blockIdx.x; tile < ntiles; tile += gridDim.x) {
        const int arow = tile * 32 + (lane & 31);
        const int arow_c = (arow < NN) ? arow : (NN - 1);  // clamped load; bad rows not stored
        f32x16 acc = {};
#pragma unroll
        for (int kc = 0; kc < 8; kc++) {
            bf16x8 a = load8(h + (size_t)arow_c * DIM + kc * 16 + khalf);
            acc = __builtin_amdgcn_mfma_f32_32x32x16_bf16(a, b[kc], acc, 0, 0, 0);
        }
#pragma unroll
        for (int r = 0; r < 16; r++) {
            int orow = tile * 32 + (r & 3) + 8 * (r >> 2) + 4 * (lane >> 5);
            if (orow < NN) t[(size_t)orow * DIM + col] = (__bf16)(acc[r] * dinv[orow]);
        }
    }
}

// ---------------- sparse: pull-gather, full-row, sentinel-padded ----------
// One wave per node; lane handles cols {2*lane, 2*lane+1}; one instruction
// reads one full 256B table row (1 contiguous segment -- the proven optimal
// shape, r10/r14/r15 A/B). Edge lists padded to x8 with sentinel row NN
// (zeros): wave-uniform bounds, zero predication. UNROLL=8 rows in flight.

__device__ __forceinline__ float lo16(unsigned u) { return __uint_as_float(u << 16); }
__device__ __forceinline__ float hi16(unsigned u) { return __uint_as_float(u & 0xffff0000u); }

__device__ __forceinline__ void gather_core(
    const unsigned* __restrict__ t32, const int* __restrict__ esrc,
    int beg, int end, int lane, float& ax, float& ay) {
    for (int e = beg; e < end; e += UNROLL) {    // end-beg is a multiple of 8
        int s[UNROLL];
        unsigned u[UNROLL];
#pragma unroll
        for (int i = 0; i < UNROLL; i++) s[i] = esrc[e + i];   // wave-uniform -> s_load
#pragma unroll
        for (int i = 0; i < UNROLL; i++) {
            const unsigned idx = ((unsigned)s[i] << 6) + lane;
            u[i] = t32[idx];
        }
#pragma unroll
        for (int i = 0; i < UNROLL; i++) {
            ax += lo16(u[i]);
            ay += hi16(u[i]);
        }
    }
}

__global__ void __launch_bounds__(256) gather_bn_kernel(
    const unsigned* __restrict__ t32, const int* __restrict__ row_ptr,
    const int* __restrict__ esrc, const float* __restrict__ dinv,
    const float* __restrict__ scale, const float* __restrict__ shift,
    __bf16* __restrict__ out) {
    const int lane = threadIdx.x & 63;
    const int n = __builtin_amdgcn_readfirstlane(blockIdx.x * 4 + (threadIdx.x >> 6));
    if (n >= NN) return;
    float ax = 0.f, ay = 0.f;
    const int beg = row_ptr[n], end = row_ptr[n + 1];
    gather_core(t32, esrc, beg, end, lane, ax, ay);
    {   // self loop (weight 1; dinv[n] applied below)
        const unsigned u = t32[((unsigned)n << 6) + lane];
        ax += lo16(u); ay += hi16(u);
    }
    const float dv = dinv[n];
    const int c0 = lane * 2, c1 = c0 + 1;
    const float vx = fmaxf(fmaf(ax, dv * scale[c0], shift[c0]), 0.f);
    const float vy = fmaxf(fmaf(ay, dv * scale[c1], shift[c1]), 0.f);
    bf16x2 o; o[0] = (__bf16)vx; o[1] = (__bf16)vy;
    *(bf16x2*)(out + (size_t)n * DIM + c0) = o;
}

// Pool: batch is SORTED -> segment reduction over RUN nodes per wave; flush
// atomics only at graph boundary / run end.

__global__ void __launch_bounds__(256) gather_pool_kernel(
    const unsigned* __restrict__ t32, const int* __restrict__ row_ptr,
    const int* __restrict__ esrc, const float* __restrict__ dinv,
    const float* __restrict__ bias, const int* __restrict__ batch,
    float* __restrict__ out) {
    const int lane = threadIdx.x & 63;
    const int wid = __builtin_amdgcn_readfirstlane(blockIdx.x * 4 + (threadIdx.x >> 6));
    const int n0 = wid * RUN;            // NN % RUN == 0
    if (n0 >= NN) return;
    const int c0 = lane * 2, c1 = c0 + 1;
    const float bx = bias[c0], by = bias[c1];
    float rx = 0.f, ry = 0.f;
    int g = batch[n0];
    for (int j = 0; j < RUN; j++) {
        const int n = n0 + j;
        float ax = 0.f, ay = 0.f;
        const int beg = row_ptr[n], end = row_ptr[n + 1];
        gather_core(t32, esrc, beg, end, lane, ax, ay);
        {
            const unsigned u = t32[((unsigned)n << 6) + lane];
            ax += lo16(u); ay += hi16(u);
        }
        const float dv = dinv[n];
        const int gn = batch[n];
        if (gn != g) {   // graph boundary: flush previous segment (uniform branch)
            atomicAdd(out + (size_t)g * DIM + c0, rx);
            atomicAdd(out + (size_t)g * DIM + c1, ry);
            rx = 0.f; ry = 0.f; g = gn;
        }
        rx += fmaf(ax, dv, bx);
        ry += fmaf(ay, dv, by);
    }
    atomicAdd(out + (size_t)g * DIM + c0, rx);
    atomicAdd(out + (size_t)g * DIM + c1, ry);
}

// ---------------- launch ----------------

extern "C" void kernel_launch(void* const* d_in, const int* in_sizes, int n_in,
                              void* d_out, int out_size, void* d_ws, size_t ws_size,
                              hipStream_t stream) {
    const float* x    = (const float*)d_in[0];
    const int*   ei   = (const int*)d_in[1];
    const int*   batch= (const int*)d_in[2];
    const float* W1 = (const float*)d_in[3];
    const float* b1 = (const float*)d_in[4];
    const float* W2 = (const float*)d_in[5];
    const float* b2 = (const float*)d_in[6];
    const float* W3 = (const float*)d_in[7];
    const float* b3 = (const float*)d_in[8];
    const float* g1 = (const float*)d_in[9];
    const float* be1= (const float*)d_in[10];
    const float* rm1= (const float*)d_in[11];
    const float* rv1= (const float*)d_in[12];
    const float* g2 = (const float*)d_in[13];
    const float* be2= (const float*)d_in[14];
    const float* rm2= (const float*)d_in[15];
    const float* rv2= (const float*)d_in[16];
    const int* erow = ei;
    const int* ecol = ei + NE;

    char* ws = (char*)d_ws;
    size_t off = 0;
    auto alloc = [&](size_t bytes) -> void* {
        void* p = ws + off;
        off = (off + bytes + 255) & ~(size_t)255;
        return p;
    };
    int*    cnt     = (int*)alloc(NN * sizeof(int));
    int*    row_ptr = (int*)alloc((NN + 1) * sizeof(int));
    int*    cursor  = (int*)alloc(NN * sizeof(int));
    int*    csum    = (int*)alloc(64 * sizeof(int));
    int*    coff    = (int*)alloc(64 * sizeof(int));
    float*  dinv    = (float*)alloc(NN * sizeof(float));
    int*    stail   = (int*)alloc(NXCD * sizeof(int));
    int*    wcnt    = (int*)alloc((size_t)NBATCH * NXCD * sizeof(int));
    int*    esrc    = (int*)alloc(NEPAD * sizeof(int));
    int2*   staging = (int2*)alloc((size_t)NXCD * SHARD_CAP * sizeof(int2));
    __bf16* tbuf    = (__bf16*)alloc((size_t)NROWS * DIM * sizeof(__bf16));
    __bf16* hbuf    = (__bf16*)alloc((size_t)NN * DIM * sizeof(__bf16));
    float*  sc1     = (float*)alloc(DIM * sizeof(float));
    float*  sh1     = (float*)alloc(DIM * sizeof(float));
    float*  sc2     = (float*)alloc(DIM * sizeof(float));
    float*  sh2     = (float*)alloc(DIM * sizeof(float));

    hipMemsetAsync(cnt, 0, NN * sizeof(int), stream);
    hipMemsetAsync(d_out, 0, NG * DIM * sizeof(float), stream);

    bn_prep_kernel<<<1, 128, 0, stream>>>(b1, g1, be1, rm1, rv1,
                                          b2, g2, be2, rm2, rv2,
                                          sc1, sh1, sc2, sh2, tbuf);
    sentinel_kernel<<<512, 256, 0, stream>>>((int4*)esrc);
    passA_kernel<<<PASS_BLOCKS, 256, 0, stream>>>(ecol, cnt, wcnt);
    sscan_kernel<<<1, 512, 0, stream>>>(wcnt, stail);
    passB_kernel<<<PASS_BLOCKS, 256, 0, stream>>>(erow, ecol, wcnt, staging);
    scan_chunk<<<NCHUNK, 256, 0, stream>>>(cnt, row_ptr, csum);
    scan_tail<<<1, 64, 0, stream>>>(csum, coff, row_ptr, NCHUNK);
    fixup_kernel<<<(NN + 255) / 256, 256, 0, stream>>>(row_ptr, coff, cnt, dinv, cursor);
    fill2_kernel<<<NXCD * FILL2_CHUNKS, 256, 0, stream>>>(staging, stail, cursor, esrc);

    const unsigned* t32 = (const unsigned*)tbuf;
    const int nblk = (NN + 3) / 4;
    const int nblk_pool = (NN / RUN + 3) / 4;

    matmul_kernel<float><<<512, 256, 0, stream>>>(x, W1, dinv, tbuf);
    gather_bn_kernel<<<nblk, 256, 0, stream>>>(t32, row_ptr, esrc, dinv,
                                               sc1, sh1, hbuf);
    matmul_kernel<__bf16><<<512, 256, 0, stream>>>(hbuf, W2, dinv, tbuf);
    gather_bn_kernel<<<nblk, 256, 0, stream>>>(t32, row_ptr, esrc, dinv,
                                               sc2, sh2, hbuf);
    matmul_kernel<__bf16><<<512, 256, 0, stream>>>(hbuf, W3, dinv, tbuf);
    gather_pool_kernel<<<nblk_pool, 256, 0, stream>>>(t32, row_ptr, esrc, dinv,
                                                      b3, batch, (float*)d_out);
}

// Round 19
// 383.756 us; speedup vs baseline: 6.7446x; 1.5835x over previous
//
#include <hip/hip_runtime.h>
#include <hip/hip_bf16.h>

#define NN 50000
#define NROWS (NN + 1)           // +1 sentinel zero row
#define NE 1600000
#define NEPAD 1951024            // >= NE + 7*NN = 1,950,000; multiple of 4
#define DIM 128
#define NG 64
#define EPSV 1e-5f
#define NCHUNK 49                // ceil(50000/1024)
#define UNROLL 8                 // table rows in flight per wave
#define RUN 4                    // nodes per wave in pool kernel
#define NXCD 8
#define SHARD_COLS (NN / NXCD)   // 6250
#define FILL_CHUNKS 256          // edge chunks; grid = 8 * FILL_CHUNKS
#define SENT_BLOCKS 512

typedef __attribute__((ext_vector_type(8))) __bf16 bf16x8;
typedef __attribute__((ext_vector_type(2))) __bf16 bf16x2;
typedef __attribute__((ext_vector_type(16))) float f32x16;

// ---------------- CSR build ----------------

// fused: sentinel prefill (blocks < SENT_BLOCKS) + int4 degree count (rest)
__global__ void count_sent_kernel(const int4* __restrict__ ecol4,
                                  int* __restrict__ cnt,
                                  int4* __restrict__ esrc4) {
    if (blockIdx.x < SENT_BLOCKS) {
        const int4 v = {NN, NN, NN, NN};
        for (int i = blockIdx.x * 256 + threadIdx.x; i < NEPAD / 4;
             i += SENT_BLOCKS * 256)
            esrc4[i] = v;
    } else {
        int i = (blockIdx.x - SENT_BLOCKS) * 256 + threadIdx.x;
        if (i < NE / 4) {
            int4 c = ecol4[i];
            atomicAdd(&cnt[c.x], 1);
            atomicAdd(&cnt[c.y], 1);
            atomicAdd(&cnt[c.z], 1);
            atomicAdd(&cnt[c.w], 1);
        }
    }
}

// scan PADDED degrees: pdeg = ceil(cnt/8)*8 (self-loop handled separately)
__global__ void scan_chunk(const int* __restrict__ cnt, int* __restrict__ excl,
                           int* __restrict__ csum) {
    __shared__ int lds[256];
    int t = threadIdx.x;
    int base = blockIdx.x * 1024 + t * 4;
    int v0 = (base + 0 < NN) ? ((cnt[base + 0] + 7) & ~7) : 0;
    int v1 = (base + 1 < NN) ? ((cnt[base + 1] + 7) & ~7) : 0;
    int v2 = (base + 2 < NN) ? ((cnt[base + 2] + 7) & ~7) : 0;
    int v3 = (base + 3 < NN) ? ((cnt[base + 3] + 7) & ~7) : 0;
    int s = v0 + v1 + v2 + v3;
    lds[t] = s;
    __syncthreads();
    for (int off = 1; off < 256; off <<= 1) {
        int x = (t >= off) ? lds[t - off] : 0;
        __syncthreads();
        lds[t] += x;
        __syncthreads();
    }
    int run = lds[t] - s;           // exclusive prefix within chunk
    if (t == 255) csum[blockIdx.x] = lds[t];
    if (base + 0 < NN) excl[base + 0] = run; run += v0;
    if (base + 1 < NN) excl[base + 1] = run; run += v1;
    if (base + 2 < NN) excl[base + 2] = run; run += v2;
    if (base + 3 < NN) excl[base + 3] = run;
}

__global__ void scan_tail(const int* __restrict__ csum, int* __restrict__ coff,
                          int* __restrict__ row_ptr, int nch) {
    int l = threadIdx.x;
    int v = (l < nch) ? csum[l] : 0;
    int s = v;
    for (int o = 1; o < 64; o <<= 1) {
        int x = __shfl_up(s, o);
        if (l >= o) s += x;
    }
    if (l < nch) coff[l] = s - v;   // exclusive chunk offsets
    if (l == nch - 1) row_ptr[NN] = s;   // total padded edges
}

__global__ void fixup_kernel(int* __restrict__ row_ptr, const int* __restrict__ coff,
                             const int* __restrict__ cnt, float* __restrict__ dinv,
                             int* __restrict__ cursor) {
    int n = blockIdx.x * 256 + threadIdx.x;
    if (n < NN) {
        int rp = row_ptr[n] + coff[n >> 10];
        row_ptr[n] = rp;
        cursor[n] = rp;
        dinv[n] = rsqrtf((float)(cnt[n] + 1));   // +1 for self-loop
    }
}

// XCD-sharded scatter: block b handles col-shard (b&7) over edge-chunk (b>>3);
// each esrc/cursor line is written by exactly one XCD -> full lines in L2.
__global__ void fill_kernel(const int* __restrict__ erow, const int* __restrict__ ecol,
                            int* __restrict__ cursor, int* __restrict__ esrc) {
    const int shard = blockIdx.x & (NXCD - 1);
    const int chunk = blockIdx.x >> 3;
    const int lo = shard * SHARD_COLS;
    const int hi = lo + SHARD_COLS;       // NN divisible by 8
    for (int e = chunk * 256 + threadIdx.x; e < NE; e += FILL_CHUNKS * 256) {
        const int c = ecol[e];
        if (c >= lo && c < hi) {
            int pos = atomicAdd(&cursor[c], 1);
            esrc[pos] = erow[e];
        }
    }
}

// fold bias+BN into per-col scale/shift; zero the sentinel row of tbuf.
__global__ void bn_prep_kernel(const float* __restrict__ b1, const float* __restrict__ g1,
                               const float* __restrict__ be1, const float* __restrict__ rm1,
                               const float* __restrict__ rv1,
                               const float* __restrict__ b2, const float* __restrict__ g2,
                               const float* __restrict__ be2, const float* __restrict__ rm2,
                               const float* __restrict__ rv2,
                               float* __restrict__ sc1, float* __restrict__ sh1,
                               float* __restrict__ sc2, float* __restrict__ sh2,
                               __bf16* __restrict__ tbuf) {
    int c = threadIdx.x;
    if (c < DIM) {
        float s1 = g1[c] * rsqrtf(rv1[c] + EPSV);
        sc1[c] = s1;
        sh1[c] = (b1[c] - rm1[c]) * s1 + be1[c];
        float s2 = g2[c] * rsqrtf(rv2[c] + EPSV);
        sc2[c] = s2;
        sh2[c] = (b2[c] - rm2[c]) * s2 + be2[c];
        tbuf[(size_t)NN * DIM + c] = (__bf16)0.f;   // sentinel row, persists all layers
    }
}

// ---------------- dense: (h @ W) * dinv[row] -> bf16 table ----------------

__device__ __forceinline__ bf16x8 load8(const float* p) {
    float4 lo = ((const float4*)p)[0], hi = ((const float4*)p)[1];
    bf16x8 a;
    a[0] = (__bf16)lo.x; a[1] = (__bf16)lo.y; a[2] = (__bf16)lo.z; a[3] = (__bf16)lo.w;
    a[4] = (__bf16)hi.x; a[5] = (__bf16)hi.y; a[6] = (__bf16)hi.z; a[7] = (__bf16)hi.w;
    return a;
}
__device__ __forceinline__ bf16x8 load8(const __bf16* p) {
    return *(const bf16x8*)p;
}

template <typename T>
__global__ void __launch_bounds__(256) matmul_kernel(const T* __restrict__ h,
                                                     const float* __restrict__ W,
                                                     const float* __restrict__ dinv,
                                                     __bf16* __restrict__ t) {
    const int wave = threadIdx.x >> 6;
    const int lane = threadIdx.x & 63;
    const int col = wave * 32 + (lane & 31);
    const int khalf = (lane >> 5) * 8;   // 0 or 8

    bf16x8 b[8];
#pragma unroll
    for (int kc = 0; kc < 8; kc++) {
#pragma unroll
        for (int j = 0; j < 8; j++) {
            b[kc][j] = (__bf16)W[(kc * 16 + khalf + j) * DIM + col];
        }
    }

    const int ntiles = (NN + 31) / 32;
    for (int tile = blockIdx.x; tile < ntiles; tile += gridDim.x) {
        const int arow = tile * 32 + (lane & 31);
        const int arow_c = (arow < NN) ? arow : (NN - 1);  // clamped load; bad rows not stored
        f32x16 acc = {};
#pragma unroll
        for (int kc = 0; kc < 8; kc++) {
            bf16x8 a = load8(h + (size_t)arow_c * DIM + kc * 16 + khalf);
            acc = __builtin_amdgcn_mfma_f32_32x32x16_bf16(a, b[kc], acc, 0, 0, 0);
        }
#pragma unroll
        for (int r = 0; r < 16; r++) {
            int orow = tile * 32 + (r & 3) + 8 * (r >> 2) + 4 * (lane >> 5);
            if (orow < NN) t[(size_t)orow * DIM + col] = (__bf16)(acc[r] * dinv[orow]);
        }
    }
}

// ---------------- sparse: pull-gather, full-row, sentinel-padded ----------
// One wave per node; lane handles cols {2*lane, 2*lane+1}; one instruction
// reads one full 256B table row (1 contiguous segment -- the proven optimal
// shape, r10/r14/r15 A/B). Edge lists padded to x8 with sentinel row NN
// (zeros): wave-uniform bounds, zero predication. UNROLL=8 rows in flight.

__device__ __forceinline__ float lo16(unsigned u) { return __uint_as_float(u << 16); }
__device__ __forceinline__ float hi16(unsigned u) { return __uint_as_float(u & 0xffff0000u); }

__device__ __forceinline__ void gather_core(
    const unsigned* __restrict__ t32, const int* __restrict__ esrc,
    int beg, int end, int lane, float& ax, float& ay) {
    for (int e = beg; e < end; e += UNROLL) {    // end-beg is a multiple of 8
        int s[UNROLL];
        unsigned u[UNROLL];
#pragma unroll
        for (int i = 0; i < UNROLL; i++) s[i] = esrc[e + i];   // wave-uniform -> s_load
#pragma unroll
        for (int i = 0; i < UNROLL; i++) {
            const unsigned idx = ((unsigned)s[i] << 6) + lane;
            u[i] = t32[idx];
        }
#pragma unroll
        for (int i = 0; i < UNROLL; i++) {
            ax += lo16(u[i]);
            ay += hi16(u[i]);
        }
    }
}

__global__ void __launch_bounds__(256) gather_bn_kernel(
    const unsigned* __restrict__ t32, const int* __restrict__ row_ptr,
    const int* __restrict__ esrc, const float* __restrict__ dinv,
    const float* __restrict__ scale, const float* __restrict__ shift,
    __bf16* __restrict__ out) {
    const int lane = threadIdx.x & 63;
    const int n = __builtin_amdgcn_readfirstlane(blockIdx.x * 4 + (threadIdx.x >> 6));
    if (n >= NN) return;
    float ax = 0.f, ay = 0.f;
    const int beg = row_ptr[n], end = row_ptr[n + 1];
    gather_core(t32, esrc, beg, end, lane, ax, ay);
    {   // self loop (weight 1; dinv[n] applied below)
        const unsigned u = t32[((unsigned)n << 6) + lane];
        ax += lo16(u); ay += hi16(u);
    }
    const float dv = dinv[n];
    const int c0 = lane * 2, c1 = c0 + 1;
    const float vx = fmaxf(fmaf(ax, dv * scale[c0], shift[c0]), 0.f);
    const float vy = fmaxf(fmaf(ay, dv * scale[c1], shift[c1]), 0.f);
    bf16x2 o; o[0] = (__bf16)vx; o[1] = (__bf16)vy;
    *(bf16x2*)(out + (size_t)n * DIM + c0) = o;
}

// Pool: batch is SORTED -> segment reduction over RUN nodes per wave; flush
// atomics only at graph boundary / run end.

__global__ void __launch_bounds__(256) gather_pool_kernel(
    const unsigned* __restrict__ t32, const int* __restrict__ row_ptr,
    const int* __restrict__ esrc, const float* __restrict__ dinv,
    const float* __restrict__ bias, const int* __restrict__ batch,
    float* __restrict__ out) {
    const int lane = threadIdx.x & 63;
    const int wid = __builtin_amdgcn_readfirstlane(blockIdx.x * 4 + (threadIdx.x >> 6));
    const int n0 = wid * RUN;            // NN % RUN == 0
    if (n0 >= NN) return;
    const int c0 = lane * 2, c1 = c0 + 1;
    const float bx = bias[c0], by = bias[c1];
    float rx = 0.f, ry = 0.f;
    int g = batch[n0];
    for (int j = 0; j < RUN; j++) {
        const int n = n0 + j;
        float ax = 0.f, ay = 0.f;
        const int beg = row_ptr[n], end = row_ptr[n + 1];
        gather_core(t32, esrc, beg, end, lane, ax, ay);
        {
            const unsigned u = t32[((unsigned)n << 6) + lane];
            ax += lo16(u); ay += hi16(u);
        }
        const float dv = dinv[n];
        const int gn = batch[n];
        if (gn != g) {   // graph boundary: flush previous segment (uniform branch)
            atomicAdd(out + (size_t)g * DIM + c0, rx);
            atomicAdd(out + (size_t)g * DIM + c1, ry);
            rx = 0.f; ry = 0.f; g = gn;
        }
        rx += fmaf(ax, dv, bx);
        ry += fmaf(ay, dv, by);
    }
    atomicAdd(out + (size_t)g * DIM + c0, rx);
    atomicAdd(out + (size_t)g * DIM + c1, ry);
}

// ---------------- launch ----------------

extern "C" void kernel_launch(void* const* d_in, const int* in_sizes, int n_in,
                              void* d_out, int out_size, void* d_ws, size_t ws_size,
                              hipStream_t stream) {
    const float* x    = (const float*)d_in[0];
    const int*   ei   = (const int*)d_in[1];
    const int*   batch= (const int*)d_in[2];
    const float* W1 = (const float*)d_in[3];
    const float* b1 = (const float*)d_in[4];
    const float* W2 = (const float*)d_in[5];
    const float* b2 = (const float*)d_in[6];
    const float* W3 = (const float*)d_in[7];
    const float* b3 = (const float*)d_in[8];
    const float* g1 = (const float*)d_in[9];
    const float* be1= (const float*)d_in[10];
    const float* rm1= (const float*)d_in[11];
    const float* rv1= (const float*)d_in[12];
    const float* g2 = (const float*)d_in[13];
    const float* be2= (const float*)d_in[14];
    const float* rm2= (const float*)d_in[15];
    const float* rv2= (const float*)d_in[16];
    const int* erow = ei;
    const int* ecol = ei + NE;

    char* ws = (char*)d_ws;
    size_t off = 0;
    auto alloc = [&](size_t bytes) -> void* {
        void* p = ws + off;
        off = (off + bytes + 255) & ~(size_t)255;
        return p;
    };
    int*    cnt     = (int*)alloc(NN * sizeof(int));
    int*    row_ptr = (int*)alloc((NN + 1) * sizeof(int));
    int*    cursor  = (int*)alloc(NN * sizeof(int));
    int*    csum    = (int*)alloc(64 * sizeof(int));
    int*    coff    = (int*)alloc(64 * sizeof(int));
    float*  dinv    = (float*)alloc(NN * sizeof(float));
    int*    esrc    = (int*)alloc(NEPAD * sizeof(int));
    __bf16* tbuf    = (__bf16*)alloc((size_t)NROWS * DIM * sizeof(__bf16));
    __bf16* hbuf    = (__bf16*)alloc((size_t)NN * DIM * sizeof(__bf16));
    float*  sc1     = (float*)alloc(DIM * sizeof(float));
    float*  sh1     = (float*)alloc(DIM * sizeof(float));
    float*  sc2     = (float*)alloc(DIM * sizeof(float));
    float*  sh2     = (float*)alloc(DIM * sizeof(float));

    hipMemsetAsync(cnt, 0, NN * sizeof(int), stream);
    hipMemsetAsync(d_out, 0, NG * DIM * sizeof(float), stream);

    bn_prep_kernel<<<1, 128, 0, stream>>>(b1, g1, be1, rm1, rv1,
                                          b2, g2, be2, rm2, rv2,
                                          sc1, sh1, sc2, sh2, tbuf);
    count_sent_kernel<<<SENT_BLOCKS + (NE / 4 + 255) / 256, 256, 0, stream>>>(
        (const int4*)ecol, cnt, (int4*)esrc);
    scan_chunk<<<NCHUNK, 256, 0, stream>>>(cnt, row_ptr, csum);
    scan_tail<<<1, 64, 0, stream>>>(csum, coff, row_ptr, NCHUNK);
    fixup_kernel<<<(NN + 255) / 256, 256, 0, stream>>>(row_ptr, coff, cnt, dinv, cursor);
    fill_kernel<<<NXCD * FILL_CHUNKS, 256, 0, stream>>>(erow, ecol, cursor, esrc);

    const unsigned* t32 = (const unsigned*)tbuf;
    const int nblk = (NN + 3) / 4;
    const int nblk_pool = (NN / RUN + 3) / 4;

    matmul_kernel<float><<<512, 256, 0, stream>>>(x, W1, dinv, tbuf);
    gather_bn_kernel<<<nblk, 256, 0, stream>>>(t32, row_ptr, esrc, dinv,
                                               sc1, sh1, hbuf);
    matmul_kernel<__bf16><<<512, 256, 0, stream>>>(hbuf, W2, dinv, tbuf);
    gather_bn_kernel<<<nblk, 256, 0, stream>>>(t32, row_ptr, esrc, dinv,
                                               sc2, sh2, hbuf);
    matmul_kernel<__bf16><<<512, 256, 0, stream>>>(hbuf, W3, dinv, tbuf);
    gather_pool_kernel<<<nblk_pool, 256, 0, stream>>>(t32, row_ptr, esrc, dinv,
                                                      b3, batch, (float*)d_out);
}